// Round 11
// baseline (157.110 us; speedup 1.0000x reference)
//
#include <hip/hip_runtime.h>
#include <math.h>

// SIREN forward: coords [N,3] -> first(3->5,sin) -> 256 x hidden(5->5,sin) -> final(5->1)
// Output layout: d_out[0..N) = net output, d_out[N..4N) = coords passthrough.
//
// Round 11: magic-number range reduction (kill quarter-rate v_rndne).
//  - Cross-round busy-cycle fit: v_sin ~19 busy cyc/wave-sin; poly w/ rndne
//    ~22 (v_rndne is ~quarter-rate, ~8cyc). Magic-add round: k=(z+C)-C with
//    C=1.5*2^23 is exact RNE for |z|<2^22, two FULL-RATE adds -> sinrev =
//    9 full-rate instrs = 18 busy cyc/sin. Saves ~160 busy cyc/SIMD-layer.
//  - Keep R10 structure: P=4, LDS-staged weights, double-buffered reg
//    prefetch (launch_bounds(256,2)), deg-9 odd Chebyshev poly (err ~3e-5),
//    weights prescaled by 30/(2pi), uniform clamp control flow.

#define SIREN_HID 5
#define SIREN_NLAYERS 256
// 30 / (2*pi)
#define SIREN_REV 4.774648292756860f
#define PTS 4
// 1.5 * 2^23: adding then subtracting rounds to nearest-even integer
#define MAGIC_RND 12582912.0f

// sin(2*pi*z) via degree-9 odd Chebyshev-truncated poly after magic-add
// range reduction. 9 full-rate VALU ops (add, sub, sub, mul, 4x fma, mul).
__device__ __forceinline__ float sinrev(float z) {
    float t  = z + MAGIC_RND;              // v_add_f32 (RNE to integer in mantissa)
    float k  = t - MAGIC_RND;              // v_sub_f32 -> k = rint(z)
    float r  = z - k;                      // exact, r in [-0.5, 0.5]
    float r2 = r * r;
    float p  = fmaf(32.768f,       r2, -74.4734720f);
    p        = fmaf(p,             r2,  81.3648896f);
    p        = fmaf(p,             r2, -41.3310592f);
    p        = fmaf(p,             r2,   6.2830548f);
    return p * r;
}

// ---------------- prep: scale weights into revolution units ----------------
// d_ws layout (floats):
//   [0 .. 8192)        hidden layers: layer l at l*32: w[0..24], b[25..29], pad
//   [8192 .. 8207)     first layer W (5x3, row-major), scaled
//   [8207 .. 8212)     first layer b, scaled
__global__ __launch_bounds__(256)
void siren_prep(const float* __restrict__ Wf, const float* __restrict__ bf,
                const float* __restrict__ Wh, const float* __restrict__ bh,
                float* __restrict__ ws)
{
    int t = blockIdx.x * blockDim.x + threadIdx.x;
    const int total = SIREN_NLAYERS * 32;
    for (int idx = t; idx < total; idx += gridDim.x * blockDim.x) {
        int l = idx >> 5;
        int k = idx & 31;
        float v = 0.0f;
        if (k < 25)      v = Wh[l * 25 + k] * SIREN_REV;
        else if (k < 30) v = bh[l * 5 + (k - 25)] * SIREN_REV;
        ws[idx] = v;
    }
    if (t < 15) ws[total + t]      = Wf[t] * SIREN_REV;
    if (t < 5)  ws[total + 15 + t] = bf[t] * SIREN_REV;
}

// load layer's 32 floats into 8 float4 regs (8x ds_read_b128)
__device__ __forceinline__ void prefetch_layer(float4 w[8], const float* slw, int l) {
    const float4* p4 = (const float4*)(slw + l * 32);
#pragma unroll
    for (int k = 0; k < 8; ++k) w[k] = p4[k];
}

// one hidden layer for all PTS points from weight regs
// layout: w0..w24 in w[0].x..w[6].x, biases b0..b4 in w[6].y..w[7].y
__device__ __forceinline__ void layer_step(float h[PTS][SIREN_HID], const float4 w[8]) {
    float z[PTS][SIREN_HID];
#pragma unroll
    for (int p = 0; p < PTS; ++p) {
        z[p][0] = fmaf(h[p][4], w[1].x, fmaf(h[p][3], w[0].w, fmaf(h[p][2], w[0].z, fmaf(h[p][1], w[0].y, fmaf(h[p][0], w[0].x, w[6].y)))));
        z[p][1] = fmaf(h[p][4], w[2].y, fmaf(h[p][3], w[2].x, fmaf(h[p][2], w[1].w, fmaf(h[p][1], w[1].z, fmaf(h[p][0], w[1].y, w[6].z)))));
        z[p][2] = fmaf(h[p][4], w[3].z, fmaf(h[p][3], w[3].y, fmaf(h[p][2], w[3].x, fmaf(h[p][1], w[2].w, fmaf(h[p][0], w[2].z, w[6].w)))));
        z[p][3] = fmaf(h[p][4], w[4].w, fmaf(h[p][3], w[4].z, fmaf(h[p][2], w[4].y, fmaf(h[p][1], w[4].x, fmaf(h[p][0], w[3].w, w[7].x)))));
        z[p][4] = fmaf(h[p][4], w[6].x, fmaf(h[p][3], w[5].w, fmaf(h[p][2], w[5].z, fmaf(h[p][1], w[5].y, fmaf(h[p][0], w[5].x, w[7].y)))));
    }
#pragma unroll
    for (int p = 0; p < PTS; ++p) {
#pragma unroll
        for (int j = 0; j < SIREN_HID; ++j)
            h[p][j] = sinrev(z[p][j]);
    }
}

// ---------------- main: 4 pts/thread, magic-poly sin, LDS + reg dbuf --------
__global__ __launch_bounds__(256, 2)
void siren_fwd11(const float* __restrict__ coords,
                 const float* __restrict__ lw,    // [256][32] scaled hidden w/b
                 const float* __restrict__ fw,    // [20] scaled first w(15)+b(5)
                 const float* __restrict__ Wfin,  // [1][5] (unscaled)
                 const float* __restrict__ bfin,  // [1]
                 float* __restrict__ out, int N)
{
    __shared__ float slw[(SIREN_NLAYERS + 1) * 32];   // +1 layer pad for last prefetch

    // cooperative stage: 2048 float4s over 256 threads (coalesced); zero the pad
    {
        const float4* g4 = (const float4*)lw;
        float4* s4 = (float4*)slw;
#pragma unroll
        for (int k = 0; k < 8; ++k)
            s4[threadIdx.x + k * 256] = g4[threadIdx.x + k * 256];
        if (threadIdx.x < 8)
            s4[2048 + threadIdx.x] = make_float4(0.f, 0.f, 0.f, 0.f);
    }
    __syncthreads();

    int i = blockIdx.x * blockDim.x + threadIdx.x;
    const int M = N / PTS;                // groups of 4 points
    i = (i < M) ? i : (M - 1);            // uniform clamp, no divergent return

    // 4 adjacent points: 48B contiguous load as 3x float4
    const float4* cp4 = (const float4*)(coords + 3 * PTS * i);
    float4 q0 = cp4[0];   // a0 a1 a2 b0
    float4 q1 = cp4[1];   // b1 b2 c0 c1
    float4 q2 = cp4[2];   // c2 d0 d1 d2
    float c[PTS][3] = {
        { q0.x, q0.y, q0.z },
        { q0.w, q1.x, q1.y },
        { q1.z, q1.w, q2.x },
        { q2.y, q2.z, q2.w },
    };

    float h[PTS][SIREN_HID];

    // first layer (revolution units): h_j = sin_rev(c . w[j,:] + b[j])
#pragma unroll
    for (int p = 0; p < PTS; ++p) {
#pragma unroll
        for (int j = 0; j < SIREN_HID; ++j) {
            float z = fmaf(c[p][2], fw[3 * j + 2],
                      fmaf(c[p][1], fw[3 * j + 1],
                      fmaf(c[p][0], fw[3 * j + 0], fw[15 + j])));
            h[p][j] = sinrev(z);
        }
    }

    // 256 hidden layers: double-buffered weight regs, prefetch one layer ahead
    float4 wa[8], wb[8];
    prefetch_layer(wa, slw, 0);
    for (int l = 0; l < SIREN_NLAYERS; l += 2) {
        prefetch_layer(wb, slw, l + 1);   // in flight during layer_step(wa)
        layer_step(h, wa);
        prefetch_layer(wa, slw, l + 2);   // l=254 -> padded zero layer, unused
        layer_step(h, wb);
    }

    // final linear (plain units, no sine)
    float w0 = Wfin[0], w1 = Wfin[1], w2 = Wfin[2], w3 = Wfin[3], w4 = Wfin[4];
    float bb = bfin[0];
    float o[PTS];
#pragma unroll
    for (int p = 0; p < PTS; ++p)
        o[p] = fmaf(h[p][4], w4, fmaf(h[p][3], w3, fmaf(h[p][2], w2, fmaf(h[p][1], w1, fmaf(h[p][0], w0, bb)))));

    // contiguous 16B store of the 4 outputs
    float4* op4 = (float4*)(out + PTS * i);
    *op4 = make_float4(o[0], o[1], o[2], o[3]);

    // coords passthrough (second tuple element), 48B contiguous
    float4* oc4 = (float4*)(out + N + 3 * PTS * i);
    oc4[0] = q0; oc4[1] = q1; oc4[2] = q2;
}

extern "C" void kernel_launch(void* const* d_in, const int* in_sizes, int n_in,
                              void* d_out, int out_size, void* d_ws, size_t ws_size,
                              hipStream_t stream) {
    const float* coords = (const float*)d_in[0];
    const float* Wf     = (const float*)d_in[1];
    const float* bf     = (const float*)d_in[2];
    const float* Wh     = (const float*)d_in[3];
    const float* bh     = (const float*)d_in[4];
    const float* Wfin   = (const float*)d_in[5];
    const float* bfin   = (const float*)d_in[6];

    int N = in_sizes[0] / 3;
    float* out = (float*)d_out;
    float* ws = (float*)d_ws;

    hipLaunchKernelGGL(siren_prep, dim3(32), dim3(256), 0, stream, Wf, bf, Wh, bh, ws);

    int M = N / PTS;                     // 4 points/thread; N=524288 -> 131072 threads
    dim3 block(256);
    dim3 grid((M + 255) / 256);
    hipLaunchKernelGGL(siren_fwd11, grid, block, 0, stream,
                       coords, ws, ws + SIREN_NLAYERS * 32, Wfin, bfin, out, N);
}